// Round 1
// baseline (148.883 us; speedup 1.0000x reference)
//
#include <hip/hip_runtime.h>

#define N_TOT  524288
#define NN1    524289
#define PP     8
#define AA     65536
#define SEGLEN 64
#define NSEG   8193      /* ceil(NN1/64) */
#define CHUNK  33        /* segments per chunk */
#define NCHK   249       /* ceil(NSEG/33) */

/* workspace offsets, in floats */
#define OFF_COORDS 0          /* N_TOT*3 = 1572864 */
#define OFF_L1G  1572864      /* NSEG*48 */
#define OFF_L1E  1966128      /* NSEG*4 ints */
#define OFF_PREG 1998900      /* NSEG*48 */
#define OFF_PREE 2392164      /* NSEG*4 ints */
#define OFF_CLG  2424936      /* NCHK*48 */
#define OFF_CLE  2436888      /* NCHK*4 ints */
#define OFF_BCG  2437884      /* NCHK*48 */

static __device__ __forceinline__ void set_ident(float* a){
  a[0]=1.f;a[1]=0.f;a[2]=0.f;a[3]=0.f;
  a[4]=0.f;a[5]=1.f;a[6]=0.f;a[7]=0.f;
  a[8]=0.f;a[9]=0.f;a[10]=1.f;a[11]=0.f;
}

/* O = A o B  (3x4 affine, row-major; child B applied after parent A: O = A@B) */
static __device__ __forceinline__ void compose(const float* Aa, const float* B, float* O){
  #pragma unroll
  for(int r=0;r<3;r++){
    float a0=Aa[r*4+0],a1=Aa[r*4+1],a2=Aa[r*4+2],a3=Aa[r*4+3];
    O[r*4+0]=a0*B[0]+a1*B[4]+a2*B[8];
    O[r*4+1]=a0*B[1]+a1*B[5]+a2*B[9];
    O[r*4+2]=a0*B[2]+a1*B[6]+a2*B[10];
    O[r*4+3]=a0*B[3]+a1*B[7]+a2*B[11]+a3;
  }
}

static __device__ __forceinline__ void load12(const float4* b4, int idx, float* a){
  float4 x=b4[idx*3+0], y=b4[idx*3+1], z=b4[idx*3+2];
  a[0]=x.x;a[1]=x.y;a[2]=x.z;a[3]=x.w;
  a[4]=y.x;a[5]=y.y;a[6]=y.z;a[7]=y.w;
  a[8]=z.x;a[9]=z.y;a[10]=z.z;a[11]=z.w;
}
static __device__ __forceinline__ void store12(float4* b4, int idx, const float* a){
  b4[idx*3+0]=make_float4(a[0],a[1],a[2],a[3]);
  b4[idx*3+1]=make_float4(a[4],a[5],a[6],a[7]);
  b4[idx*3+2]=make_float4(a[8],a[9],a[10],a[11]);
}

/* Serial walk over [i0, i0+count). Window W[j] = transform of node (i-4+j)
   (relative in K1, absolute in K4), We[j] = exit tag. */
static __device__ __forceinline__ void do_walk(
    int i0, int count,
    const float* __restrict__ masked, const float4* __restrict__ base4,
    const int* __restrict__ parents, const int* __restrict__ kin,
    float* __restrict__ coords, bool storePos,
    float W[4][12], int We[4])
{
  #pragma unroll 4
  for(int k=0;k<count;++k){
    int i = i0 + k;
    float G[12]; int e;
    if(i==0){
      set_ident(G); e=3;
    } else {
      float4 b = base4[i];
      float phi = masked[i];
      float sp,cp,st,ct;
      __sincosf(phi,&sp,&cp);
      __sincosf(b.y,&st,&ct);
      float dd = b.z;
      int p = parents[i];
      int j = p - i + 4;            /* in 0..3 by construction */
      float S[12];
      #pragma unroll
      for(int q=0;q<12;q++){
        float lo = (j==0)? W[0][q] : W[1][q];
        float hi = (j==2)? W[2][q] : W[3][q];
        S[q] = (j<2)? lo : hi;
      }
      e = (j<2)? ((j==0)?We[0]:We[1]) : ((j==2)?We[2]:We[3]);
      /* local M: Rz(phi)Ry(theta)Tx(d); col1 has a structural 0, t = d*col0 */
      float m0=cp*ct, m1=-sp, m2=cp*st;
      float m4=sp*ct, m5=cp,  m6=sp*st;
      float m8=-st,   m10=ct;
      #pragma unroll
      for(int r=0;r<3;r++){
        float a0=S[r*4+0],a1=S[r*4+1],a2=S[r*4+2],a3=S[r*4+3];
        float g0=a0*m0+a1*m4+a2*m8;
        float g1=a0*m1+a1*m5;
        float g2=a0*m2+a1*m6+a2*m10;
        G[r*4+0]=g0; G[r*4+1]=g1; G[r*4+2]=g2;
        G[r*4+3]=dd*g0+a3;
      }
    }
    if(storePos && i>0){
      int dst = kin[i-1];
      coords[dst*3+0]=G[3]; coords[dst*3+1]=G[7]; coords[dst*3+2]=G[11];
    }
    #pragma unroll
    for(int q=0;q<12;q++){ W[0][q]=W[1][q]; W[1][q]=W[2][q]; W[2][q]=W[3][q]; W[3][q]=G[q]; }
    We[0]=We[1]; We[1]=We[2]; We[2]=We[3]; We[3]=e;
  }
}

/* K1: per-segment relative walk -> segment link (last-4 window) */
__global__ void k1_seg(const float* __restrict__ masked, const float4* __restrict__ base4,
                       const int* __restrict__ parents,
                       float4* __restrict__ L1G, int* __restrict__ L1E)
{
  int s = blockIdx.x*blockDim.x + threadIdx.x;
  if(s >= NSEG) return;
  int i0 = s*SEGLEN;
  int count = min(SEGLEN, NN1 - i0);
  float W[4][12]; int We[4];
  #pragma unroll
  for(int j=0;j<4;j++){ set_ident(W[j]); We[j]=j; }
  do_walk(i0,count,masked,base4,parents,nullptr,nullptr,false,W,We);
  #pragma unroll
  for(int j=0;j<4;j++){ store12(L1G, s*4+j, W[j]); L1E[s*4+j]=We[j]; }
}

/* K2: 4 lanes per chunk; serial combine of 33 segment links, storing
   per-segment exclusive prefixes; emits chunk link. */
__global__ void k2_chunk(const float4* __restrict__ L1G, const int* __restrict__ L1E,
                         float4* __restrict__ PREG, int* __restrict__ PREE,
                         float4* __restrict__ CLG, int* __restrict__ CLE)
{
  int t = blockIdx.x*blockDim.x + threadIdx.x;
  int g = t>>2, j = t&3;
  if(g >= NCHK) return;
  int lane = threadIdx.x & 63;
  int laneBase = lane & ~3;
  int s0 = g*CHUNK;
  int ns = min(CHUNK, NSEG - s0);
  float acc[12]; set_ident(acc);
  int ae = j;
  for(int q=0;q<ns;q++){
    int s = s0+q;
    store12(PREG, s*4+j, acc);
    PREE[s*4+j] = ae;
    float lg[12]; load12(L1G, s*4+j, lg);
    int le = L1E[s*4+j];
    int srcLane = laneBase + le;
    float src[12];
    #pragma unroll
    for(int q2=0;q2<12;q2++) src[q2] = __shfl(acc[q2], srcLane, 64);
    int se = __shfl(ae, srcLane, 64);
    float nw[12]; compose(src, lg, nw);
    #pragma unroll
    for(int q2=0;q2<12;q2++) acc[q2]=nw[q2];
    ae = se;
  }
  store12(CLG, g*4+j, acc);
  CLE[g*4+j] = ae;
}

/* K3: single-block doubling scan over NCHK chunk links; emits exclusive
   chunk-start boundary states (applied to identity => just the g's). */
__global__ void k3_scan(const float4* __restrict__ CLG, const int* __restrict__ CLE,
                        float4* __restrict__ BCG)
{
  __shared__ float Lg[NCHK*48];
  __shared__ int   Le[NCHK*4];
  int t = threadIdx.x;
  int g = t>>2, j = t&3;
  bool act = (g < NCHK);
  if(act){
    float a[12]; load12(CLG, g*4+j, a);
    #pragma unroll
    for(int q=0;q<12;q++) Lg[g*48+j*12+q]=a[q];
    Le[g*4+j] = CLE[g*4+j];
  }
  __syncthreads();
  for(int d=1; d<NCHK; d<<=1){
    float ng[12]; int ne=0;
    bool doit = act && (g>=d);
    if(doit){
      int myE = Le[g*4+j];
      float own[12], pg[12];
      #pragma unroll
      for(int q=0;q<12;q++) own[q]=Lg[g*48+j*12+q];
      #pragma unroll
      for(int q=0;q<12;q++) pg[q]=Lg[(g-d)*48+myE*12+q];
      compose(pg, own, ng);
      ne = Le[(g-d)*4+myE];
    }
    __syncthreads();
    if(doit){
      #pragma unroll
      for(int q=0;q<12;q++) Lg[g*48+j*12+q]=ng[q];
      Le[g*4+j]=ne;
    }
    __syncthreads();
  }
  if(act){
    float b[12];
    if(g==0){ set_ident(b); }
    else {
      #pragma unroll
      for(int q=0;q<12;q++) b[q]=Lg[(g-1)*48+j*12+q];
    }
    store12(BCG, g*4+j, b);
  }
}

/* K4: absolute re-walk per segment; scatter positions through kin_id */
__global__ void k4_pos(const float* __restrict__ masked, const float4* __restrict__ base4,
                       const int* __restrict__ parents, const int* __restrict__ kin,
                       const float4* __restrict__ PREG, const int* __restrict__ PREE,
                       const float4* __restrict__ BCG,
                       float* __restrict__ coords)
{
  int s = blockIdx.x*blockDim.x + threadIdx.x;
  if(s >= NSEG) return;
  int c = s / CHUNK;
  float W[4][12]; int We[4];
  #pragma unroll
  for(int j=0;j<4;j++){
    int e = PREE[s*4+j];
    float bg[12], pg[12];
    load12(BCG, c*4+e, bg);
    load12(PREG, s*4+j, pg);
    compose(bg, pg, W[j]);
    We[j]=j;
  }
  int i0 = s*SEGLEN;
  int count = min(SEGLEN, NN1 - i0);
  do_walk(i0,count,masked,base4,parents,kin,coords,true,W,We);
}

/* K5: bond energy; 32 blocks per pose, LDS+shfl reduce, atomicAdd */
__global__ void k5_energy(const float* __restrict__ coords, const float* __restrict__ bw,
                          float* __restrict__ out)
{
  int p = blockIdx.x >> 5;
  int sub = blockIdx.x & 31;
  int a0 = sub * 2048;
  int aend = min(a0 + 2048, AA - 1);
  float sum = 0.f;
  for(int a = a0 + (int)threadIdx.x; a < aend; a += 256){
    int r = p*AA + a;
    float dx = coords[(r+1)*3+0]-coords[r*3+0];
    float dy = coords[(r+1)*3+1]-coords[r*3+1];
    float dz = coords[(r+1)*3+2]-coords[r*3+2];
    sum += bw[p*(AA-1)+a]*(dx*dx+dy*dy+dz*dz);
  }
  #pragma unroll
  for(int off=32;off>0;off>>=1) sum += __shfl_down(sum, off, 64);
  __shared__ float red[4];
  int lane = threadIdx.x & 63, wid = threadIdx.x >> 6;
  if(lane==0) red[wid]=sum;
  __syncthreads();
  if(threadIdx.x==0){
    float tot = red[0]+red[1]+red[2]+red[3];
    atomicAdd(&out[p], tot);
  }
}

extern "C" void kernel_launch(void* const* d_in, const int* in_sizes, int n_in,
                              void* d_out, int out_size, void* d_ws, size_t ws_size,
                              hipStream_t stream)
{
  const float* masked  = (const float*)d_in[0];
  const float* base    = (const float*)d_in[1];
  /* d_in[2] pose_coords unused: kin_id is a full permutation */
  const float* bw      = (const float*)d_in[3];
  const int*   parents = (const int*)d_in[4];
  const int*   kin     = (const int*)d_in[5];

  float* ws = (float*)d_ws;
  float* coords = ws + OFF_COORDS;
  float4* L1G = (float4*)(ws + OFF_L1G);
  int*    L1E = (int*)(ws + OFF_L1E);
  float4* PREG= (float4*)(ws + OFF_PREG);
  int*    PREE= (int*)(ws + OFF_PREE);
  float4* CLG = (float4*)(ws + OFF_CLG);
  int*    CLE = (int*)(ws + OFF_CLE);
  float4* BCG = (float4*)(ws + OFF_BCG);

  const float4* base4 = (const float4*)base;

  hipMemsetAsync(d_out, 0, out_size*sizeof(float), stream);

  k1_seg<<<(NSEG+255)/256, 256, 0, stream>>>(masked, base4, parents, L1G, L1E);
  k2_chunk<<<(NCHK*4+255)/256, 256, 0, stream>>>(L1G, L1E, PREG, PREE, CLG, CLE);
  k3_scan<<<1, 1024, 0, stream>>>(CLG, CLE, BCG);
  k4_pos<<<(NSEG+255)/256, 256, 0, stream>>>(masked, base4, parents, kin, PREG, PREE, BCG, coords);
  k5_energy<<<PP*32, 256, 0, stream>>>(coords, bw, (float*)d_out);
}

// Round 2
// 75.710 us; speedup vs baseline: 1.9665x; 1.9665x over previous
//
#include <hip/hip_runtime.h>

#define NN1    524289
#define PP     8
#define AA     65536
#define SEGLEN 64
#define NSEG   8193      /* ceil(NN1/64) */
#define CHUNK  33        /* segments per chunk */
#define NCHK   249       /* ceil(NSEG/33) */

/* workspace offsets, in floats (same proven footprint as round 0) */
#define OFF_COORDS 0          /* 524288*3 = 1572864 */
#define OFF_L1G  1572864      /* NSEG*48 */
#define OFF_L1E  1966128      /* NSEG*4 ints */
#define OFF_PREG 1998900      /* NSEG*48 */
#define OFF_PREE 2392164      /* NSEG*4 ints */
#define OFF_CLG  2424936      /* NCHK*48 */
#define OFF_CLE  2436888      /* NCHK*4 ints */
#define OFF_BCG  2437884      /* NCHK*48 */

static __device__ __forceinline__ void set_ident(float* a){
  a[0]=1.f;a[1]=0.f;a[2]=0.f;a[3]=0.f;
  a[4]=0.f;a[5]=1.f;a[6]=0.f;a[7]=0.f;
  a[8]=0.f;a[9]=0.f;a[10]=1.f;a[11]=0.f;
}

/* O = A @ B  (3x4 affine, row-major) */
static __device__ __forceinline__ void compose(const float* Aa, const float* B, float* O){
  #pragma unroll
  for(int r=0;r<3;r++){
    float a0=Aa[r*4+0],a1=Aa[r*4+1],a2=Aa[r*4+2],a3=Aa[r*4+3];
    O[r*4+0]=a0*B[0]+a1*B[4]+a2*B[8];
    O[r*4+1]=a0*B[1]+a1*B[5]+a2*B[9];
    O[r*4+2]=a0*B[2]+a1*B[6]+a2*B[10];
    O[r*4+3]=a0*B[3]+a1*B[7]+a2*B[11]+a3;
  }
}

static __device__ __forceinline__ void load12(const float4* b4, int idx, float* a){
  float4 x=b4[idx*3+0], y=b4[idx*3+1], z=b4[idx*3+2];
  a[0]=x.x;a[1]=x.y;a[2]=x.z;a[3]=x.w;
  a[4]=y.x;a[5]=y.y;a[6]=y.z;a[7]=y.w;
  a[8]=z.x;a[9]=z.y;a[10]=z.z;a[11]=z.w;
}
static __device__ __forceinline__ void store12(float4* b4, int idx, const float* a){
  b4[idx*3+0]=make_float4(a[0],a[1],a[2],a[3]);
  b4[idx*3+1]=make_float4(a[4],a[5],a[6],a[7]);
  b4[idx*3+2]=make_float4(a[8],a[9],a[10],a[11]);
}

/* Wave-parallel doubling scan for one 64-node segment.
   On exit: G = relative transform of lane's node w.r.t. its entry slot,
   pk>>8 = entry tag (0..3 = node i0-4+tag). pk&0xFF==0xFF (all done). */
static __device__ __forceinline__ void wave_scan(
    int w, int lane,
    const float* __restrict__ masked, const float4* __restrict__ base4,
    const int* __restrict__ parents,
    float G[12], int& pk)
{
  int i0 = w*SEGLEN;
  int i = i0 + lane;
  if(i == 0 || i >= NN1){
    set_ident(G); pk = 0xFF;                 /* done, tag 0 */
  } else {
    float4 b = base4[i];
    float phi = masked[i];
    float sp,cp,st,ct;
    __sincosf(phi,&sp,&cp);
    __sincosf(b.y,&st,&ct);
    float dd = b.z;
    G[0]=cp*ct; G[1]=-sp; G[2]=cp*st; G[3]=dd*G[0];
    G[4]=sp*ct; G[5]=cp;  G[6]=sp*st; G[7]=dd*G[4];
    G[8]=-st;   G[9]=0.f; G[10]=ct;   G[11]=dd*G[8];
    int rel = parents[i] - i0;
    pk = (rel >= 0) ? rel : (((rel+4)<<8) | 0xFF);
  }
  #pragma unroll
  for(int step=0; step<6; ++step){
    int ptr = pk & 0xFF;
    bool act = (ptr != 0xFF);
    int src = act ? ptr : lane;
    float g2[12];
    #pragma unroll
    for(int q=0;q<12;q++) g2[q] = __shfl(G[q], src, 64);
    int pk2 = __shfl(pk, src, 64);
    float ng[12];
    compose(g2, G, ng);
    #pragma unroll
    for(int q=0;q<12;q++) G[q] = act ? ng[q] : G[q];
    pk = act ? pk2 : pk;
  }
}

/* K1: per-segment link = relative transforms of exit nodes (lanes 60..63) */
__global__ void k1_links(const float* __restrict__ masked, const float4* __restrict__ base4,
                         const int* __restrict__ parents,
                         float4* __restrict__ L1G, int* __restrict__ L1E)
{
  int w = blockIdx.x*(blockDim.x>>6) + (threadIdx.x>>6);
  if(w >= NSEG) return;
  int lane = threadIdx.x & 63;
  float G[12]; int pk;
  wave_scan(w, lane, masked, base4, parents, G, pk);
  if(lane >= 60){
    int j = lane - 60;
    store12(L1G, w*4+j, G);
    L1E[w*4+j] = (pk>>8)&0xFF;
  }
}

/* K2: 4 lanes per chunk; serial combine of 33 segment links -> per-segment
   chunk-relative exclusive prefixes + chunk link. */
__global__ void k2_chunk(const float4* __restrict__ L1G, const int* __restrict__ L1E,
                         float4* __restrict__ PREG, int* __restrict__ PREE,
                         float4* __restrict__ CLG, int* __restrict__ CLE)
{
  int t = blockIdx.x*blockDim.x + threadIdx.x;
  int g = t>>2, j = t&3;
  if(g >= NCHK) return;
  int lane = threadIdx.x & 63;
  int laneBase = lane & ~3;
  int s0 = g*CHUNK;
  int ns = min(CHUNK, NSEG - s0);
  float acc[12]; set_ident(acc);
  int ae = j;
  for(int q=0;q<ns;q++){
    int s = s0+q;
    store12(PREG, s*4+j, acc);
    PREE[s*4+j] = ae;
    float lg[12]; load12(L1G, s*4+j, lg);
    int le = L1E[s*4+j];
    int srcLane = laneBase + le;
    float src[12];
    #pragma unroll
    for(int q2=0;q2<12;q2++) src[q2] = __shfl(acc[q2], srcLane, 64);
    int se = __shfl(ae, srcLane, 64);
    float nw[12]; compose(src, lg, nw);
    #pragma unroll
    for(int q2=0;q2<12;q2++) acc[q2]=nw[q2];
    ae = se;
  }
  store12(CLG, g*4+j, acc);
  CLE[g*4+j] = ae;
}

/* K3: single-block doubling scan over NCHK chunk links -> chunk-start states */
__global__ void k3_scan(const float4* __restrict__ CLG, const int* __restrict__ CLE,
                        float4* __restrict__ BCG)
{
  __shared__ float Lg[NCHK*48];
  __shared__ int   Le[NCHK*4];
  int t = threadIdx.x;
  int g = t>>2, j = t&3;
  bool act = (g < NCHK);
  if(act){
    float a[12]; load12(CLG, g*4+j, a);
    #pragma unroll
    for(int q=0;q<12;q++) Lg[g*48+j*12+q]=a[q];
    Le[g*4+j] = CLE[g*4+j];
  }
  __syncthreads();
  for(int d=1; d<NCHK; d<<=1){
    float ng[12]; int ne=0;
    bool doit = act && (g>=d);
    if(doit){
      int myE = Le[g*4+j];
      float own[12], pg[12];
      #pragma unroll
      for(int q=0;q<12;q++) own[q]=Lg[g*48+j*12+q];
      #pragma unroll
      for(int q=0;q<12;q++) pg[q]=Lg[(g-d)*48+myE*12+q];
      compose(pg, own, ng);
      ne = Le[(g-d)*4+myE];
    }
    __syncthreads();
    if(doit){
      #pragma unroll
      for(int q=0;q<12;q++) Lg[g*48+j*12+q]=ng[q];
      Le[g*4+j]=ne;
    }
    __syncthreads();
  }
  if(act){
    float b[12];
    if(g==0){ set_ident(b); }
    else {
      #pragma unroll
      for(int q=0;q<12;q++) b[q]=Lg[(g-1)*48+j*12+q];
    }
    store12(BCG, g*4+j, b);
  }
}

/* K4: re-run wave scan, apply absolute boundary, scatter coords via kin_id */
__global__ void k4_pos(const float* __restrict__ masked, const float4* __restrict__ base4,
                       const int* __restrict__ parents, const int* __restrict__ kin,
                       const float4* __restrict__ PREG, const int* __restrict__ PREE,
                       const float4* __restrict__ BCG,
                       float* __restrict__ coords)
{
  int w = blockIdx.x*(blockDim.x>>6) + (threadIdx.x>>6);
  if(w >= NSEG) return;
  int lane = threadIdx.x & 63;
  float G[12]; int pk;
  wave_scan(w, lane, masked, base4, parents, G, pk);
  int i = w*SEGLEN + lane;
  if(i == 0 || i >= NN1) return;
  int tag = (pk>>8)&0xFF;
  int c = w / CHUNK;
  int e = PREE[w*4+tag];
  float bg[12], pg[12];
  load12(BCG, c*4+e, bg);
  load12(PREG, w*4+tag, pg);
  float A[12]; compose(bg, pg, A);
  float t0=G[3], t1=G[7], t2=G[11];
  float x = A[0]*t0 + A[1]*t1 + A[2]*t2  + A[3];
  float y = A[4]*t0 + A[5]*t1 + A[6]*t2  + A[7];
  float z = A[8]*t0 + A[9]*t1 + A[10]*t2 + A[11];
  int dst = kin[i-1];
  coords[dst*3+0]=x; coords[dst*3+1]=y; coords[dst*3+2]=z;
}

/* K5: bond energy; 32 blocks per pose, shfl+LDS reduce, atomicAdd */
__global__ void k5_energy(const float* __restrict__ coords, const float* __restrict__ bw,
                          float* __restrict__ out)
{
  int p = blockIdx.x >> 5;
  int sub = blockIdx.x & 31;
  int a0 = sub * 2048;
  int aend = min(a0 + 2048, AA - 1);
  float sum = 0.f;
  for(int a = a0 + (int)threadIdx.x; a < aend; a += 256){
    int r = p*AA + a;
    float dx = coords[(r+1)*3+0]-coords[r*3+0];
    float dy = coords[(r+1)*3+1]-coords[r*3+1];
    float dz = coords[(r+1)*3+2]-coords[r*3+2];
    sum += bw[p*(AA-1)+a]*(dx*dx+dy*dy+dz*dz);
  }
  #pragma unroll
  for(int off=32;off>0;off>>=1) sum += __shfl_down(sum, off, 64);
  __shared__ float red[4];
  int lane = threadIdx.x & 63, wid = threadIdx.x >> 6;
  if(lane==0) red[wid]=sum;
  __syncthreads();
  if(threadIdx.x==0){
    float tot = red[0]+red[1]+red[2]+red[3];
    atomicAdd(&out[p], tot);
  }
}

extern "C" void kernel_launch(void* const* d_in, const int* in_sizes, int n_in,
                              void* d_out, int out_size, void* d_ws, size_t ws_size,
                              hipStream_t stream)
{
  const float* masked  = (const float*)d_in[0];
  const float* base    = (const float*)d_in[1];
  /* d_in[2] pose_coords unused: kin_id is a full permutation */
  const float* bw      = (const float*)d_in[3];
  const int*   parents = (const int*)d_in[4];
  const int*   kin     = (const int*)d_in[5];

  float* ws = (float*)d_ws;
  float* coords = ws + OFF_COORDS;
  float4* L1G = (float4*)(ws + OFF_L1G);
  int*    L1E = (int*)(ws + OFF_L1E);
  float4* PREG= (float4*)(ws + OFF_PREG);
  int*    PREE= (int*)(ws + OFF_PREE);
  float4* CLG = (float4*)(ws + OFF_CLG);
  int*    CLE = (int*)(ws + OFF_CLE);
  float4* BCG = (float4*)(ws + OFF_BCG);

  const float4* base4 = (const float4*)base;

  hipMemsetAsync(d_out, 0, out_size*sizeof(float), stream);

  /* 4 waves / 256-thread block; one wave per 64-node segment */
  int nblk = (NSEG + 3) / 4;
  k1_links<<<nblk, 256, 0, stream>>>(masked, base4, parents, L1G, L1E);
  k2_chunk<<<(NCHK*4+255)/256, 256, 0, stream>>>(L1G, L1E, PREG, PREE, CLG, CLE);
  k3_scan<<<1, 1024, 0, stream>>>(CLG, CLE, BCG);
  k4_pos<<<nblk, 256, 0, stream>>>(masked, base4, parents, kin, PREG, PREE, BCG, coords);
  k5_energy<<<PP*32, 256, 0, stream>>>(coords, bw, (float*)d_out);
}

// Round 3
// 72.245 us; speedup vs baseline: 2.0608x; 1.0480x over previous
//
#include <hip/hip_runtime.h>

#define NN1    524289
#define PP     8
#define AA     65536
#define SEGLEN 64
#define NSEG   8193      /* ceil(NN1/64) */
#define CHUNK  33        /* segments per chunk */
#define NCHK   249       /* ceil(NSEG/33) */

/* workspace offsets, in floats */
#define OFF_COORDS 0          /* float4[524288]  = 2097152 floats */
#define OFF_NT   2097152      /* float4[NN1]     = 2097156 floats */
#define OFF_L1G  4194308      /* NSEG*48 */
#define OFF_L1E  4587572      /* NSEG*4 ints */
#define OFF_PREG 4620344      /* NSEG*48 */
#define OFF_PREE 5013608      /* NSEG*4 ints */
#define OFF_CLG  5046380      /* NCHK*48 */
#define OFF_CLE  5058332      /* NCHK*4 ints */
#define OFF_BCG  5059328      /* NCHK*48 */

static __device__ __forceinline__ void set_ident(float* a){
  a[0]=1.f;a[1]=0.f;a[2]=0.f;a[3]=0.f;
  a[4]=0.f;a[5]=1.f;a[6]=0.f;a[7]=0.f;
  a[8]=0.f;a[9]=0.f;a[10]=1.f;a[11]=0.f;
}

/* O = A @ B  (3x4 affine, row-major) */
static __device__ __forceinline__ void compose(const float* Aa, const float* B, float* O){
  #pragma unroll
  for(int r=0;r<3;r++){
    float a0=Aa[r*4+0],a1=Aa[r*4+1],a2=Aa[r*4+2],a3=Aa[r*4+3];
    O[r*4+0]=a0*B[0]+a1*B[4]+a2*B[8];
    O[r*4+1]=a0*B[1]+a1*B[5]+a2*B[9];
    O[r*4+2]=a0*B[2]+a1*B[6]+a2*B[10];
    O[r*4+3]=a0*B[3]+a1*B[7]+a2*B[11]+a3;
  }
}

static __device__ __forceinline__ void load12(const float4* b4, int idx, float* a){
  float4 x=b4[idx*3+0], y=b4[idx*3+1], z=b4[idx*3+2];
  a[0]=x.x;a[1]=x.y;a[2]=x.z;a[3]=x.w;
  a[4]=y.x;a[5]=y.y;a[6]=y.z;a[7]=y.w;
  a[8]=z.x;a[9]=z.y;a[10]=z.z;a[11]=z.w;
}
static __device__ __forceinline__ void store12(float4* b4, int idx, const float* a){
  b4[idx*3+0]=make_float4(a[0],a[1],a[2],a[3]);
  b4[idx*3+1]=make_float4(a[4],a[5],a[6],a[7]);
  b4[idx*3+2]=make_float4(a[8],a[9],a[10],a[11]);
}

/* Wave-parallel doubling scan for one 64-node segment.
   On exit: G = relative transform of lane's node w.r.t. its entry slot,
   pk>>8 = entry tag (0..3 = node i0-4+tag), pk&0xFF==0xFF (resolved). */
static __device__ __forceinline__ void wave_scan(
    int w, int lane,
    const float* __restrict__ masked, const float4* __restrict__ base4,
    const int* __restrict__ parents,
    float G[12], int& pk)
{
  int i0 = w*SEGLEN;
  int i = i0 + lane;
  if(i == 0 || i >= NN1){
    set_ident(G); pk = 0xFF;                 /* done, tag 0 */
  } else {
    float4 b = base4[i];
    float phi = masked[i];
    float sp,cp,st,ct;
    __sincosf(phi,&sp,&cp);
    __sincosf(b.y,&st,&ct);
    float dd = b.z;
    G[0]=cp*ct; G[1]=-sp; G[2]=cp*st; G[3]=dd*G[0];
    G[4]=sp*ct; G[5]=cp;  G[6]=sp*st; G[7]=dd*G[4];
    G[8]=-st;   G[9]=0.f; G[10]=ct;   G[11]=dd*G[8];
    int rel = parents[i] - i0;
    pk = (rel >= 0) ? rel : (((rel+4)<<8) | 0xFF);
  }
  #pragma unroll
  for(int step=0; step<6; ++step){
    int ptr = pk & 0xFF;
    bool act = (ptr != 0xFF);
    int src = act ? ptr : lane;
    float g2[12];
    #pragma unroll
    for(int q=0;q<12;q++) g2[q] = __shfl(G[q], src, 64);
    int pk2 = __shfl(pk, src, 64);
    float ng[12];
    compose(g2, G, ng);
    #pragma unroll
    for(int q=0;q<12;q++) G[q] = act ? ng[q] : G[q];
    pk = act ? pk2 : pk;
  }
}

/* K1: full wave scan; store per-node (t_rel, tag) and per-segment links.
   Also zero-inits d_out (stream-ordered before k5's atomics). */
__global__ void k1_links(const float* __restrict__ masked, const float4* __restrict__ base4,
                         const int* __restrict__ parents,
                         float4* __restrict__ L1G, int* __restrict__ L1E,
                         float4* __restrict__ NT, float* __restrict__ out)
{
  if(blockIdx.x==0 && threadIdx.x < PP) out[threadIdx.x] = 0.f;
  int w = blockIdx.x*(blockDim.x>>6) + (threadIdx.x>>6);
  if(w >= NSEG) return;
  int lane = threadIdx.x & 63;
  float G[12]; int pk;
  wave_scan(w, lane, masked, base4, parents, G, pk);
  int i = w*SEGLEN + lane;
  int tag = (pk>>8)&0xFF;
  if(i < NN1){
    NT[i] = make_float4(G[3], G[7], G[11], __int_as_float(tag));
  }
  if(lane >= 60){
    int j = lane - 60;
    store12(L1G, w*4+j, G);
    L1E[w*4+j] = tag;
  }
}

/* K2: 4 lanes per chunk; serial combine of 33 segment links -> per-segment
   chunk-relative exclusive prefixes + chunk link. */
__global__ void k2_chunk(const float4* __restrict__ L1G, const int* __restrict__ L1E,
                         float4* __restrict__ PREG, int* __restrict__ PREE,
                         float4* __restrict__ CLG, int* __restrict__ CLE)
{
  int t = blockIdx.x*blockDim.x + threadIdx.x;
  int g = t>>2, j = t&3;
  if(g >= NCHK) return;
  int lane = threadIdx.x & 63;
  int laneBase = lane & ~3;
  int s0 = g*CHUNK;
  int ns = min(CHUNK, NSEG - s0);
  float acc[12]; set_ident(acc);
  int ae = j;
  for(int q=0;q<ns;q++){
    int s = s0+q;
    store12(PREG, s*4+j, acc);
    PREE[s*4+j] = ae;
    float lg[12]; load12(L1G, s*4+j, lg);
    int le = L1E[s*4+j];
    int srcLane = laneBase + le;
    float src[12];
    #pragma unroll
    for(int q2=0;q2<12;q2++) src[q2] = __shfl(acc[q2], srcLane, 64);
    int se = __shfl(ae, srcLane, 64);
    float nw[12]; compose(src, lg, nw);
    #pragma unroll
    for(int q2=0;q2<12;q2++) acc[q2]=nw[q2];
    ae = se;
  }
  store12(CLG, g*4+j, acc);
  CLE[g*4+j] = ae;
}

/* K3: single-block doubling scan over NCHK chunk links -> chunk-start states */
__global__ void k3_scan(const float4* __restrict__ CLG, const int* __restrict__ CLE,
                        float4* __restrict__ BCG)
{
  __shared__ float Lg[NCHK*48];
  __shared__ int   Le[NCHK*4];
  int t = threadIdx.x;
  int g = t>>2, j = t&3;
  bool act = (g < NCHK);
  if(act){
    float a[12]; load12(CLG, g*4+j, a);
    #pragma unroll
    for(int q=0;q<12;q++) Lg[g*48+j*12+q]=a[q];
    Le[g*4+j] = CLE[g*4+j];
  }
  __syncthreads();
  for(int d=1; d<NCHK; d<<=1){
    float ng[12]; int ne=0;
    bool doit = act && (g>=d);
    if(doit){
      int myE = Le[g*4+j];
      float own[12], pg[12];
      #pragma unroll
      for(int q=0;q<12;q++) own[q]=Lg[g*48+j*12+q];
      #pragma unroll
      for(int q=0;q<12;q++) pg[q]=Lg[(g-d)*48+myE*12+q];
      compose(pg, own, ng);
      ne = Le[(g-d)*4+myE];
    }
    __syncthreads();
    if(doit){
      #pragma unroll
      for(int q=0;q<12;q++) Lg[g*48+j*12+q]=ng[q];
      Le[g*4+j]=ne;
    }
    __syncthreads();
  }
  if(act){
    float b[12];
    if(g==0){ set_ident(b); }
    else {
      #pragma unroll
      for(int q=0;q<12;q++) b[q]=Lg[(g-1)*48+j*12+q];
    }
    store12(BCG, g*4+j, b);
  }
}

/* K4: apply absolute entry transform to stored (t_rel, tag); scatter via kin_id */
__global__ void k4_pos(const int* __restrict__ kin, const float4* __restrict__ NT,
                       const float4* __restrict__ PREG, const int* __restrict__ PREE,
                       const float4* __restrict__ BCG,
                       float4* __restrict__ coords)
{
  int w = blockIdx.x*(blockDim.x>>6) + (threadIdx.x>>6);
  if(w >= NSEG) return;
  int lane = threadIdx.x & 63;
  int i = w*SEGLEN + lane;
  if(i == 0 || i >= NN1) return;
  float4 nt = NT[i];
  int tag = __float_as_int(nt.w) & 3;
  int c = w / CHUNK;
  int e = PREE[w*4+tag];
  float bg[12], pg[12], A[12];
  load12(BCG, c*4+e, bg);          /* L1/L2 broadcast across wave */
  load12(PREG, w*4+tag, pg);
  compose(bg, pg, A);
  float x = A[0]*nt.x + A[1]*nt.y + A[2]*nt.z  + A[3];
  float y = A[4]*nt.x + A[5]*nt.y + A[6]*nt.z  + A[7];
  float z = A[8]*nt.x + A[9]*nt.y + A[10]*nt.z + A[11];
  coords[kin[i-1]] = make_float4(x, y, z, 0.f);
}

/* K5: bond energy; 32 blocks per pose, shfl+LDS reduce, atomicAdd */
__global__ void k5_energy(const float4* __restrict__ coords, const float* __restrict__ bw,
                          float* __restrict__ out)
{
  int p = blockIdx.x >> 5;
  int sub = blockIdx.x & 31;
  int a0 = sub * 2048;
  int aend = min(a0 + 2048, AA - 1);
  float sum = 0.f;
  for(int a = a0 + (int)threadIdx.x; a < aend; a += 256){
    int r = p*AA + a;
    float4 c0 = coords[r], c1 = coords[r+1];
    float dx = c1.x-c0.x, dy = c1.y-c0.y, dz = c1.z-c0.z;
    sum += bw[p*(AA-1)+a]*(dx*dx+dy*dy+dz*dz);
  }
  #pragma unroll
  for(int off=32;off>0;off>>=1) sum += __shfl_down(sum, off, 64);
  __shared__ float red[4];
  int lane = threadIdx.x & 63, wid = threadIdx.x >> 6;
  if(lane==0) red[wid]=sum;
  __syncthreads();
  if(threadIdx.x==0){
    float tot = red[0]+red[1]+red[2]+red[3];
    atomicAdd(&out[p], tot);
  }
}

extern "C" void kernel_launch(void* const* d_in, const int* in_sizes, int n_in,
                              void* d_out, int out_size, void* d_ws, size_t ws_size,
                              hipStream_t stream)
{
  const float* masked  = (const float*)d_in[0];
  const float* base    = (const float*)d_in[1];
  /* d_in[2] pose_coords unused: kin_id is a full permutation */
  const float* bw      = (const float*)d_in[3];
  const int*   parents = (const int*)d_in[4];
  const int*   kin     = (const int*)d_in[5];

  float* ws = (float*)d_ws;
  float4* coords = (float4*)(ws + OFF_COORDS);
  float4* NT  = (float4*)(ws + OFF_NT);
  float4* L1G = (float4*)(ws + OFF_L1G);
  int*    L1E = (int*)(ws + OFF_L1E);
  float4* PREG= (float4*)(ws + OFF_PREG);
  int*    PREE= (int*)(ws + OFF_PREE);
  float4* CLG = (float4*)(ws + OFF_CLG);
  int*    CLE = (int*)(ws + OFF_CLE);
  float4* BCG = (float4*)(ws + OFF_BCG);

  const float4* base4 = (const float4*)base;

  int nblk = (NSEG + 3) / 4;   /* 4 waves per 256-thread block */
  k1_links<<<nblk, 256, 0, stream>>>(masked, base4, parents, L1G, L1E, NT, (float*)d_out);
  k2_chunk<<<(NCHK*4+255)/256, 256, 0, stream>>>(L1G, L1E, PREG, PREE, CLG, CLE);
  k3_scan<<<1, 1024, 0, stream>>>(CLG, CLE, BCG);
  k4_pos<<<nblk, 256, 0, stream>>>(kin, NT, PREG, PREE, BCG, coords);
  k5_energy<<<PP*32, 256, 0, stream>>>(coords, bw, (float*)d_out);
}